// Round 1
// baseline (690.175 us; speedup 1.0000x reference)
//
#include <hip/hip_runtime.h>

#define HH 4
#define FF 128
#define DD 32

// m stored as monotonically-ordered int keys so atomicMax(int) == float max.
// key = bits ^ ((bits>>31) & 0x7fffffff); involution, order-preserving.
__device__ __forceinline__ int f2key(float v) {
    int ix = __float_as_int(v);
    return ix ^ ((ix >> 31) & 0x7fffffff);
}
__device__ __forceinline__ float key2f(int key) {
    int ix = key ^ ((key >> 31) & 0x7fffffff);
    return __int_as_float(ix);
}

__global__ void init_kernel(int* __restrict__ mk, float* __restrict__ denom, int n) {
    int i = blockIdx.x * blockDim.x + threadIdx.x;
    if (i < n) { mk[i] = (int)0x80000000; denom[i] = 0.0f; }
}

// q[n,h,d] = sum_f feat[n,f] * w_q[h,f,d]; same for k with w_k.
// 32 entities per block; feats staged in LDS; each thread owns one (h,d)
// output column of q OR k across all 32 entities (weights read once/block).
__global__ __launch_bounds__(256) void qk_kernel(
    const float* __restrict__ feat, const float* __restrict__ wq,
    const float* __restrict__ wk, float* __restrict__ q,
    float* __restrict__ k, int N) {
    __shared__ float fs[32 * FF];
    int n0 = blockIdx.x * 32;
    int nb = N - n0; if (nb > 32) nb = 32;
    const float4* s4 = (const float4*)(feat + (size_t)n0 * FF);
    int nf4 = nb * FF / 4;
    for (int i = threadIdx.x; i < nf4; i += 256) ((float4*)fs)[i] = s4[i];
    __syncthreads();

    int isK = threadIdx.x >> 7;      // 0 -> q, 1 -> k
    int o   = threadIdx.x & 127;
    int h = o >> 5, d = o & 31;
    const float* w = (isK ? wk : wq) + ((size_t)h * FF) * DD + d;

    float acc[32];
#pragma unroll
    for (int e = 0; e < 32; ++e) acc[e] = 0.f;
    for (int f = 0; f < FF; f += 4) {
        float w0 = w[(f + 0) * DD], w1 = w[(f + 1) * DD];
        float w2 = w[(f + 2) * DD], w3 = w[(f + 3) * DD];
#pragma unroll
        for (int e = 0; e < 32; ++e) {
            float4 fv = *(const float4*)&fs[e * FF + f];
            acc[e] += fv.x * w0 + fv.y * w1 + fv.z * w2 + fv.w * w3;
        }
    }
    float* outp = isK ? k : q;
    for (int e = 0; e < nb; ++e)
        outp[((size_t)(n0 + e) * HH + h) * DD + d] = acc[e];
}

// kk[n,h,f] = sum_d w_k[h,f,d] * k[n,h,d]. 16 entities/block; k in LDS.
// Thread o owns (h=o>>7, f=o&127) and (h+2, f) for all 16 entities.
__global__ __launch_bounds__(256) void kk_kernel(
    const float* __restrict__ k, const float* __restrict__ wk,
    float* __restrict__ kk, int N) {
    __shared__ float ks[16 * FF];
    int n0 = blockIdx.x * 16;
    int nb = N - n0; if (nb > 16) nb = 16;
    const float4* s4 = (const float4*)(k + (size_t)n0 * FF);
    int nf4 = nb * FF / 4;
    for (int i = threadIdx.x; i < nf4; i += 256) ((float4*)ks)[i] = s4[i];
    __syncthreads();

    int o = threadIdx.x;
    int h1 = o >> 7, f1 = o & 127;
    int h2 = h1 + 2;
    const float* w1 = wk + ((size_t)h1 * FF + f1) * DD;
    const float* w2 = wk + ((size_t)h2 * FF + f1) * DD;

    float acc1[16], acc2[16];
#pragma unroll
    for (int e = 0; e < 16; ++e) { acc1[e] = 0.f; acc2[e] = 0.f; }
    for (int d = 0; d < DD; d += 4) {
        float4 wv1 = *(const float4*)&w1[d];
        float4 wv2 = *(const float4*)&w2[d];
#pragma unroll
        for (int e = 0; e < 16; ++e) {
            float4 k1 = *(const float4*)&ks[e * FF + h1 * DD + d];
            float4 k2 = *(const float4*)&ks[e * FF + h2 * DD + d];
            acc1[e] += k1.x * wv1.x + k1.y * wv1.y + k1.z * wv1.z + k1.w * wv1.w;
            acc2[e] += k2.x * wv2.x + k2.y * wv2.y + k2.z * wv2.z + k2.w * wv2.w;
        }
    }
    for (int e = 0; e < nb; ++e) {
        kk[((size_t)(n0 + e) * HH + h1) * FF + f1] = acc1[e];
        kk[((size_t)(n0 + e) * HH + h2) * FF + f1] = acc2[e];
    }
}

// One wave per edge; 4 groups of 16 lanes, one head each.
// e[edge,h] = k[dst,h]·q[src,h] + rel[edge]·kk[src,h]; leaky_relu; atomicMax m.
__global__ __launch_bounds__(256) void edge_kernel(
    const float* __restrict__ rel, const int* __restrict__ src,
    const int* __restrict__ dst, const float* __restrict__ q,
    const float* __restrict__ k, const float* __restrict__ kk,
    float* __restrict__ ebuf, int* __restrict__ mk, int E) {
    int edge = (blockIdx.x * 256 + threadIdx.x) >> 6;
    if (edge >= E) return;
    int lane = threadIdx.x & 63;
    int g = lane >> 4;   // head
    int t = lane & 15;
    int s = src[edge], d = dst[edge];

    const float* relp = rel + (size_t)edge * FF + t * 8;
    const float* kkp  = kk + ((size_t)s * HH + g) * FF + t * 8;
    float4 r0 = *(const float4*)relp;
    float4 r1 = *(const float4*)(relp + 4);
    float4 c0 = *(const float4*)kkp;
    float4 c1 = *(const float4*)(kkp + 4);
    float acc = r0.x * c0.x + r0.y * c0.y + r0.z * c0.z + r0.w * c0.w
              + r1.x * c1.x + r1.y * c1.y + r1.z * c1.z + r1.w * c1.w;

    const float* qp = q + ((size_t)s * HH + g) * DD + t * 2;
    const float* kp = k + ((size_t)d * HH + g) * DD + t * 2;
    float2 qv = *(const float2*)qp;
    float2 kv = *(const float2*)kp;
    acc += qv.x * kv.x + qv.y * kv.y;

#pragma unroll
    for (int off = 1; off < 16; off <<= 1) acc += __shfl_xor(acc, off, 64);

    if (t == 0) {
        float ev = acc >= 0.f ? acc : 0.01f * acc;   // leaky_relu(0.01)
        ebuf[(size_t)edge * HH + g] = ev;
        atomicMax(&mk[s * HH + g], f2key(ev));
    }
}

// ex = exp(e - m[src]); accumulate denominator.
__global__ void pass3_kernel(float* __restrict__ ebuf, const int* __restrict__ src,
                             const int* __restrict__ mk, float* __restrict__ denom,
                             int EH) {
    int i = blockIdx.x * blockDim.x + threadIdx.x;
    if (i >= EH) return;
    int edge = i >> 2, h = i & 3;
    int s = src[edge];
    float m = key2f(mk[s * HH + h]);
    float ex = __expf(ebuf[i] - m);
    ebuf[i] = ex;
    atomicAdd(&denom[s * HH + h], ex);
}

// out[edge] = (1/H) * sum_h ex[edge,h] / denom[src,h]
__global__ void pass4_kernel(const float* __restrict__ ebuf, const int* __restrict__ src,
                             const float* __restrict__ denom, float* __restrict__ out,
                             int E) {
    int edge = blockIdx.x * blockDim.x + threadIdx.x;
    if (edge >= E) return;
    float4 ex = *(const float4*)&ebuf[(size_t)edge * 4];
    int s = src[edge];
    float4 dn = *(const float4*)&denom[(size_t)s * 4];
    out[edge] = 0.25f * (ex.x / dn.x + ex.y / dn.y + ex.z / dn.z + ex.w / dn.w);
}

extern "C" void kernel_launch(void* const* d_in, const int* in_sizes, int n_in,
                              void* d_out, int out_size, void* d_ws, size_t ws_size,
                              hipStream_t stream) {
    const float* feat = (const float*)d_in[0];   // (N,1,F)
    const float* rel  = (const float*)d_in[1];   // (E,1,F)
    const int*   src  = (const int*)d_in[2];
    const int*   dst  = (const int*)d_in[3];
    const float* wq   = (const float*)d_in[4];   // (H,F,D)
    const float* wk   = (const float*)d_in[5];
    float* out = (float*)d_out;

    const int N = in_sizes[0] / FF;
    const int E = in_sizes[2];

    // workspace layout (fp32 elements): total ~171.2 MB
    float* q     = (float*)d_ws;                 // N*H*D
    float* k     = q  + (size_t)N * HH * DD;     // N*H*D
    float* kk    = k  + (size_t)N * HH * DD;     // N*H*F
    float* ebuf  = kk + (size_t)N * HH * FF;     // E*H
    int*   mk    = (int*)(ebuf + (size_t)E * HH);// N*H
    float* denom = (float*)(mk + (size_t)N * HH);// N*H

    int NH = N * HH;
    init_kernel<<<(NH + 255) / 256, 256, 0, stream>>>(mk, denom, NH);
    qk_kernel<<<(N + 31) / 32, 256, 0, stream>>>(feat, wq, wk, q, k, N);
    kk_kernel<<<(N + 15) / 16, 256, 0, stream>>>(k, wk, kk, N);
    edge_kernel<<<(E + 3) / 4, 256, 0, stream>>>(rel, src, dst, q, k, kk, ebuf, mk, E);
    long long EH = (long long)E * HH;
    pass3_kernel<<<(int)((EH + 255) / 256), 256, 0, stream>>>(ebuf, src, mk, denom, (int)EH);
    pass4_kernel<<<(E + 255) / 256, 256, 0, stream>>>(ebuf, src, denom, out, E);
}

// Round 2
// 452.548 us; speedup vs baseline: 1.5251x; 1.5251x over previous
//
#include <hip/hip_runtime.h>

#define HH 4
#define FF 128
#define DD 32
#define MAXDEG 128   // max edges/src staged in LDS (Poisson(20) over 50k srcs -> max ~45; tail path below handles overflow)

// ---------------- counting sort: histogram + scan + scatter ----------------

__global__ void zero_kernel(int* __restrict__ c, int n) {
    int i = blockIdx.x * blockDim.x + threadIdx.x;
    if (i < n) c[i] = 0;
}

__global__ void hist_kernel(const int* __restrict__ src, int* __restrict__ counts, int E) {
    int i = blockIdx.x * blockDim.x + threadIdx.x;
    if (i < E) atomicAdd(&counts[src[i]], 1);
}

__global__ __launch_bounds__(256) void scan_block_kernel(
    const int* __restrict__ counts, int* __restrict__ start,
    int* __restrict__ partial, int N) {
    __shared__ int sm[256];
    int t = threadIdx.x;
    int gid = blockIdx.x * 256 + t;
    int v = gid < N ? counts[gid] : 0;
    sm[t] = v; __syncthreads();
    for (int off = 1; off < 256; off <<= 1) {
        int x = (t >= off) ? sm[t - off] : 0;
        __syncthreads();
        sm[t] += x;
        __syncthreads();
    }
    if (gid < N) start[gid] = sm[t] - v;      // exclusive within block
    if (t == 255) partial[blockIdx.x] = sm[t];
}

__global__ __launch_bounds__(256) void scan_partial_kernel(int* __restrict__ partial, int nb) {
    __shared__ int sm[256];
    int t = threadIdx.x;
    int v = (t < nb) ? partial[t] : 0;
    sm[t] = v; __syncthreads();
    for (int off = 1; off < 256; off <<= 1) {
        int x = (t >= off) ? sm[t - off] : 0;
        __syncthreads();
        sm[t] += x;
        __syncthreads();
    }
    if (t < nb) partial[t] = sm[t] - v;       // exclusive
}

__global__ void addback_kernel(int* __restrict__ start, int* __restrict__ cursor,
                               const int* __restrict__ partial, int N) {
    int gid = blockIdx.x * 256 + threadIdx.x;
    if (gid < N) {
        int s = start[gid] + partial[blockIdx.x];
        start[gid] = s;
        cursor[gid] = s;
    }
}

__global__ void scatter_kernel(const int* __restrict__ src, const int* __restrict__ dst,
                               int* __restrict__ cursor, int* __restrict__ perm,
                               int* __restrict__ dsts, int E) {
    int i = blockIdx.x * blockDim.x + threadIdx.x;
    if (i >= E) return;
    int s = src[i];
    int pos = atomicAdd(&cursor[s], 1);
    perm[pos] = i;
    dsts[pos] = dst[i];
}

// ---------------- projections (unchanged from round 1) ----------------

__global__ __launch_bounds__(256) void qk_kernel(
    const float* __restrict__ feat, const float* __restrict__ wq,
    const float* __restrict__ wk, float* __restrict__ q,
    float* __restrict__ k, int N) {
    __shared__ float fs[32 * FF];
    int n0 = blockIdx.x * 32;
    int nb = N - n0; if (nb > 32) nb = 32;
    const float4* s4 = (const float4*)(feat + (size_t)n0 * FF);
    int nf4 = nb * FF / 4;
    for (int i = threadIdx.x; i < nf4; i += 256) ((float4*)fs)[i] = s4[i];
    __syncthreads();

    int isK = threadIdx.x >> 7;
    int o   = threadIdx.x & 127;
    int h = o >> 5, d = o & 31;
    const float* w = (isK ? wk : wq) + ((size_t)h * FF) * DD + d;

    float acc[32];
#pragma unroll
    for (int e = 0; e < 32; ++e) acc[e] = 0.f;
    for (int f = 0; f < FF; f += 4) {
        float w0 = w[(f + 0) * DD], w1 = w[(f + 1) * DD];
        float w2 = w[(f + 2) * DD], w3 = w[(f + 3) * DD];
#pragma unroll
        for (int e = 0; e < 32; ++e) {
            float4 fv = *(const float4*)&fs[e * FF + f];
            acc[e] += fv.x * w0 + fv.y * w1 + fv.z * w2 + fv.w * w3;
        }
    }
    float* outp = isK ? k : q;
    for (int e = 0; e < nb; ++e)
        outp[((size_t)(n0 + e) * HH + h) * DD + d] = acc[e];
}

__global__ __launch_bounds__(256) void kk_kernel(
    const float* __restrict__ k, const float* __restrict__ wk,
    float* __restrict__ kk, int N) {
    __shared__ float ks[16 * FF];
    int n0 = blockIdx.x * 16;
    int nb = N - n0; if (nb > 16) nb = 16;
    const float4* s4 = (const float4*)(k + (size_t)n0 * FF);
    int nf4 = nb * FF / 4;
    for (int i = threadIdx.x; i < nf4; i += 256) ((float4*)ks)[i] = s4[i];
    __syncthreads();

    int o = threadIdx.x;
    int h1 = o >> 7, f1 = o & 127;
    int h2 = h1 + 2;
    const float* w1 = wk + ((size_t)h1 * FF + f1) * DD;
    const float* w2 = wk + ((size_t)h2 * FF + f1) * DD;

    float acc1[16], acc2[16];
#pragma unroll
    for (int e = 0; e < 16; ++e) { acc1[e] = 0.f; acc2[e] = 0.f; }
    for (int d = 0; d < DD; d += 4) {
        float4 wv1 = *(const float4*)&w1[d];
        float4 wv2 = *(const float4*)&w2[d];
#pragma unroll
        for (int e = 0; e < 16; ++e) {
            float4 k1 = *(const float4*)&ks[e * FF + h1 * DD + d];
            float4 k2 = *(const float4*)&ks[e * FF + h2 * DD + d];
            acc1[e] += k1.x * wv1.x + k1.y * wv1.y + k1.z * wv1.z + k1.w * wv1.w;
            acc2[e] += k2.x * wv2.x + k2.y * wv2.y + k2.z * wv2.z + k2.w * wv2.w;
        }
    }
    for (int e = 0; e < nb; ++e) {
        kk[((size_t)(n0 + e) * HH + h1) * FF + f1] = acc1[e];
        kk[((size_t)(n0 + e) * HH + h2) * FF + f1] = acc2[e];
    }
}

// ---------------- fused per-src group kernel ----------------
// One wave per src. Lane (g,t): head g (4 groups), slot t (16 lanes).
// kk[src,g], q[src,g] live in registers for the whole group.
// e = rel[edge]·kk[src] + q[src]·k[dst]; leaky_relu; online softmax in regs;
// e staged in LDS; final att written directly (no atomics, no ebuf).

__device__ __forceinline__ float edge_score(
    const float* __restrict__ rel, const float* __restrict__ k,
    int e, int dd, int g, int t, float4 kkA, float4 kkB, float2 qv) {
    const float* relp = rel + (size_t)e * FF + t * 8;
    float4 r0 = *(const float4*)relp;
    float4 r1 = *(const float4*)(relp + 4);
    const float* kp = k + ((size_t)dd * HH + g) * DD + t * 2;
    float2 kv = *(const float2*)kp;
    float acc = r0.x * kkA.x + r0.y * kkA.y + r0.z * kkA.z + r0.w * kkA.w
              + r1.x * kkB.x + r1.y * kkB.y + r1.z * kkB.z + r1.w * kkB.w
              + qv.x * kv.x + qv.y * kv.y;
#pragma unroll
    for (int off = 1; off < 16; off <<= 1) acc += __shfl_xor(acc, off, 64);
    return acc >= 0.f ? acc : 0.01f * acc;   // leaky_relu(0.01)
}

__global__ __launch_bounds__(64) void group_kernel(
    const float* __restrict__ rel, const int* __restrict__ perm,
    const int* __restrict__ dsts, const float* __restrict__ q,
    const float* __restrict__ k, const float* __restrict__ kk,
    const int* __restrict__ start, const int* __restrict__ counts,
    float* __restrict__ out, int N) {
    int s = blockIdx.x;
    int cnt = counts[s];
    if (cnt == 0) return;
    int base = start[s];
    int lane = threadIdx.x, g = lane >> 4, t = lane & 15;

    const float* kkp = kk + ((size_t)s * HH + g) * FF + t * 8;
    float4 kkA = *(const float4*)kkp;
    float4 kkB = *(const float4*)(kkp + 4);
    float2 qv  = *(const float2*)(q + ((size_t)s * HH + g) * DD + t * 2);

    __shared__ float e_lds[HH * MAXDEG];
    float m = -INFINITY, l = 0.f;

    for (int i0 = 0; i0 < cnt; i0 += 16) {
        int i = i0 + t;
        int pv = 0, dv = 0;
        if (i < cnt) { pv = perm[base + i]; dv = dsts[base + i]; }
        int lim = cnt - i0; if (lim > 16) lim = 16;
        for (int j = 0; j < lim; ++j) {
            int e  = __shfl(pv, j, 16);
            int dd = __shfl(dv, j, 16);
            float ev = edge_score(rel, k, e, dd, g, t, kkA, kkB, qv);
            if (t == 0 && (i0 + j) < MAXDEG) e_lds[g * MAXDEG + i0 + j] = ev;
            float nm = fmaxf(m, ev);
            l = l * __expf(m - nm) + __expf(ev - nm);
            m = nm;
        }
    }
    __syncthreads();

    float invl = 1.f / l;
    int cl = cnt < MAXDEG ? cnt : MAXDEG;
    for (int i0 = 0; i0 < cl; i0 += 16) {
        int i = i0 + t;
        float v = 0.f;
        if (i < cl) v = __expf(e_lds[g * MAXDEG + i] - m) * invl;
        float sum = v;
        sum += __shfl_xor(sum, 16, 64);
        sum += __shfl_xor(sum, 32, 64);
        if (g == 0 && i < cl) out[perm[base + i]] = 0.25f * sum;
    }
    // overflow tail (practically never taken; keeps correctness unconditional)
    for (int i = MAXDEG; i < cnt; ++i) {
        int e = perm[base + i], dd = dsts[base + i];
        float ev = edge_score(rel, k, e, dd, g, t, kkA, kkB, qv);
        float v = __expf(ev - m) * invl;
        float sum = v;
        sum += __shfl_xor(sum, 16, 64);
        sum += __shfl_xor(sum, 32, 64);
        if (lane == 0) out[e] = 0.25f * sum;
    }
}

extern "C" void kernel_launch(void* const* d_in, const int* in_sizes, int n_in,
                              void* d_out, int out_size, void* d_ws, size_t ws_size,
                              hipStream_t stream) {
    const float* feat = (const float*)d_in[0];   // (N,1,F)
    const float* rel  = (const float*)d_in[1];   // (E,1,F)
    const int*   src  = (const int*)d_in[2];
    const int*   dst  = (const int*)d_in[3];
    const float* wq   = (const float*)d_in[4];   // (H,F,D)
    const float* wk   = (const float*)d_in[5];
    float* out = (float*)d_out;

    const int N = in_sizes[0] / FF;
    const int E = in_sizes[2];

    // workspace layout (~163 MB)
    float* q      = (float*)d_ws;                     // N*H*D
    float* k      = q  + (size_t)N * HH * DD;         // N*H*D
    float* kk     = k  + (size_t)N * HH * DD;         // N*H*F
    int*   counts = (int*)(kk + (size_t)N * HH * FF); // N
    int*   start  = counts + N;                       // N
    int*   cursor = start + N;                        // N
    int*   partial= cursor + N;                       // 256
    int*   perm   = partial + 256;                    // E
    int*   dsts   = perm + E;                         // E

    int nb = (N + 255) / 256;   // 196 <= 256, fits single-block partial scan
    zero_kernel<<<nb, 256, 0, stream>>>(counts, N);
    hist_kernel<<<(E + 255) / 256, 256, 0, stream>>>(src, counts, E);
    scan_block_kernel<<<nb, 256, 0, stream>>>(counts, start, partial, N);
    scan_partial_kernel<<<1, 256, 0, stream>>>(partial, nb);
    addback_kernel<<<nb, 256, 0, stream>>>(start, cursor, partial, N);
    scatter_kernel<<<(E + 255) / 256, 256, 0, stream>>>(src, dst, cursor, perm, dsts, E);

    qk_kernel<<<(N + 31) / 32, 256, 0, stream>>>(feat, wq, wk, q, k, N);
    kk_kernel<<<(N + 15) / 16, 256, 0, stream>>>(k, wk, kk, N);

    group_kernel<<<N, 64, 0, stream>>>(rel, perm, dsts, q, k, kk, start, counts, out, N);
}

// Round 4
// 416.256 us; speedup vs baseline: 1.6581x; 1.0872x over previous
//
#include <hip/hip_runtime.h>

#define HH 4
#define FF 128
#define DD 32

typedef float f32x4 __attribute__((ext_vector_type(4)));

// ---------------- sort helper kernels ----------------

__global__ void zero_kernel(int* __restrict__ c, int n) {
    int i = blockIdx.x * blockDim.x + threadIdx.x;
    if (i < n) c[i] = 0;
}

__global__ __launch_bounds__(256) void scan_partial_kernel(int* __restrict__ partial, int nb) {
    __shared__ int sm[256];
    int t = threadIdx.x;
    int v = (t < nb) ? partial[t] : 0;
    sm[t] = v; __syncthreads();
    for (int off = 1; off < 256; off <<= 1) {
        int x = (t >= off) ? sm[t - off] : 0;
        __syncthreads();
        sm[t] += x;
        __syncthreads();
    }
    if (t < nb) partial[t] = sm[t] - v;       // exclusive
}

__global__ void addback_kernel(int* __restrict__ start, int* __restrict__ cursor,
                               const int* __restrict__ partial, int N) {
    int gid = blockIdx.x * 256 + threadIdx.x;
    if (gid < N) {
        int s = start[gid] + partial[blockIdx.x];
        start[gid] = s;
        cursor[gid] = s;
    }
}

__global__ void scatter_kernel(const int* __restrict__ src, const int* __restrict__ dst,
                               int* __restrict__ cursor, int* __restrict__ perm,
                               int* __restrict__ dsts, int E) {
    int i = blockIdx.x * blockDim.x + threadIdx.x;
    if (i >= E) return;
    int s = src[i];
    int pos = atomicAdd(&cursor[s], 1);
    perm[pos] = i;
    dsts[pos] = dst[i];
}

// ---------------- fused: qk projection + histogram ----------------

__global__ __launch_bounds__(256) void qk_hist_kernel(
    const float* __restrict__ feat, const float* __restrict__ wq,
    const float* __restrict__ wk, float* __restrict__ q,
    float* __restrict__ k, int N,
    const int* __restrict__ src, int* __restrict__ counts, int E, int QKB) {
    __shared__ float fs[32 * FF];
    int bid = blockIdx.x;
    if (bid >= QKB) {           // ---- histogram role ----
        int i = ((bid - QKB) * 256 + threadIdx.x) * 4;
        if (i + 3 < E) {
            int4 v = *(const int4*)(src + i);
            atomicAdd(&counts[v.x], 1);
            atomicAdd(&counts[v.y], 1);
            atomicAdd(&counts[v.z], 1);
            atomicAdd(&counts[v.w], 1);
        } else {
            for (; i < E; ++i) atomicAdd(&counts[src[i]], 1);
        }
        return;
    }
    // ---- qk role ----
    int n0 = bid * 32;
    int nb = N - n0; if (nb > 32) nb = 32;
    const float4* s4 = (const float4*)(feat + (size_t)n0 * FF);
    int nf4 = nb * FF / 4;
    for (int i = threadIdx.x; i < nf4; i += 256) ((float4*)fs)[i] = s4[i];
    __syncthreads();

    int isK = threadIdx.x >> 7;
    int o   = threadIdx.x & 127;
    int h = o >> 5, d = o & 31;
    const float* w = (isK ? wk : wq) + ((size_t)h * FF) * DD + d;

    float acc[32];
#pragma unroll
    for (int e = 0; e < 32; ++e) acc[e] = 0.f;
    for (int f = 0; f < FF; f += 4) {
        float w0 = w[(f + 0) * DD], w1 = w[(f + 1) * DD];
        float w2 = w[(f + 2) * DD], w3 = w[(f + 3) * DD];
#pragma unroll
        for (int e = 0; e < 32; ++e) {
            float4 fv = *(const float4*)&fs[e * FF + f];
            acc[e] += fv.x * w0 + fv.y * w1 + fv.z * w2 + fv.w * w3;
        }
    }
    float* outp = isK ? k : q;
    for (int e = 0; e < nb; ++e)
        outp[((size_t)(n0 + e) * HH + h) * DD + d] = acc[e];
}

// ---------------- fused: kk projection + block scan ----------------

__global__ __launch_bounds__(256) void kk_scan_kernel(
    const float* __restrict__ kbuf, const float* __restrict__ wk,
    float* __restrict__ kkout, int N,
    const int* __restrict__ counts, int* __restrict__ startb,
    int* __restrict__ partial, int KKB) {
    __shared__ float ks[16 * FF];
    __shared__ int sm[256];
    int bid = blockIdx.x;
    if (bid >= KKB) {           // ---- scan_block role ----
        int b = bid - KKB;
        int tid = threadIdx.x;
        int gid = b * 256 + tid;
        int v = gid < N ? counts[gid] : 0;
        sm[tid] = v; __syncthreads();
        for (int off = 1; off < 256; off <<= 1) {
            int x = (tid >= off) ? sm[tid - off] : 0;
            __syncthreads();
            sm[tid] += x;
            __syncthreads();
        }
        if (gid < N) startb[gid] = sm[tid] - v;
        if (tid == 255) partial[b] = sm[tid];
        return;
    }
    // ---- kk role ----
    int n0 = bid * 16;
    int nb = N - n0; if (nb > 16) nb = 16;
    const float4* s4 = (const float4*)(kbuf + (size_t)n0 * FF);
    int nf4 = nb * FF / 4;
    for (int i = threadIdx.x; i < nf4; i += 256) ((float4*)ks)[i] = s4[i];
    __syncthreads();

    int o = threadIdx.x;
    int h1 = o >> 7, f1 = o & 127;
    int h2 = h1 + 2;
    const float* w1 = wk + ((size_t)h1 * FF + f1) * DD;
    const float* w2 = wk + ((size_t)h2 * FF + f1) * DD;

    float acc1[16], acc2[16];
#pragma unroll
    for (int e = 0; e < 16; ++e) { acc1[e] = 0.f; acc2[e] = 0.f; }
    for (int d = 0; d < DD; d += 4) {
        float4 wv1 = *(const float4*)&w1[d];
        float4 wv2 = *(const float4*)&w2[d];
#pragma unroll
        for (int e = 0; e < 16; ++e) {
            float4 k1 = *(const float4*)&ks[e * FF + h1 * DD + d];
            float4 k2 = *(const float4*)&ks[e * FF + h2 * DD + d];
            acc1[e] += k1.x * wv1.x + k1.y * wv1.y + k1.z * wv1.z + k1.w * wv1.w;
            acc2[e] += k2.x * wv2.x + k2.y * wv2.y + k2.z * wv2.z + k2.w * wv2.w;
        }
    }
    for (int e = 0; e < nb; ++e) {
        kkout[((size_t)(n0 + e) * HH + h1) * FF + f1] = acc1[e];
        kkout[((size_t)(n0 + e) * HH + h2) * FF + f1] = acc2[e];
    }
}

// ---------------- group kernel v3 ----------------
// One wave per src; 4 lane-groups each score a DIFFERENT edge per step (rel
// read exactly once -> nontemporal), each lane holds kk/q for ALL 4 heads.

__device__ __forceinline__ int score4(
    const float* __restrict__ rel, const float* __restrict__ k,
    int pv, int dv, int j0, int g, int t,
    const float4* kkA, const float4* kkB, const float2* qv,
    float* ev, int* e_i_out) {
    int idx = j0 + g;
    int e_i = __shfl(pv, idx, 64);
    int dd  = __shfl(dv, idx, 64);
    *e_i_out = e_i;
    const float* rp = rel + (size_t)e_i * FF + t * 8;
    f32x4 r0 = __builtin_nontemporal_load((const f32x4*)rp);
    f32x4 r1 = __builtin_nontemporal_load((const f32x4*)(rp + 4));
#pragma unroll
    for (int h = 0; h < HH; ++h) {
        float2 kv = *(const float2*)(k + ((size_t)dd * HH + h) * DD + t * 2);
        float a = r0.x * kkA[h].x + r0.y * kkA[h].y + r0.z * kkA[h].z + r0.w * kkA[h].w
                + r1.x * kkB[h].x + r1.y * kkB[h].y + r1.z * kkB[h].z + r1.w * kkB[h].w
                + qv[h].x * kv.x + qv[h].y * kv.y;
#pragma unroll
        for (int off = 1; off < 16; off <<= 1) a += __shfl_xor(a, off, 64);
        ev[h] = a >= 0.f ? a : 0.01f * a;    // leaky_relu(0.01)
    }
    return idx;
}

__global__ __launch_bounds__(256) void group_kernel(
    const float* __restrict__ rel, const int* __restrict__ perm,
    const int* __restrict__ dsts, const float* __restrict__ q,
    const float* __restrict__ k, const float* __restrict__ kk,
    const int* __restrict__ start, const int* __restrict__ counts,
    float* __restrict__ out, int N) {
    __shared__ __align__(16) float e_buf_all[4][128][4];
    int wid = threadIdx.x >> 6;
    int s = blockIdx.x * 4 + wid;
    if (s >= N) return;
    int cnt = counts[s];
    if (cnt == 0) return;
    int base = start[s];
    int lane = threadIdx.x & 63;
    int g = lane >> 4, t = lane & 15;
    float (*e_buf)[4] = e_buf_all[wid];

    float4 kkA[HH], kkB[HH];
    float2 qv[HH];
    const float* kkbase = kk + (size_t)s * (HH * FF) + t * 8;
    const float* qbase  = q  + (size_t)s * (HH * DD) + t * 2;
#pragma unroll
    for (int h = 0; h < HH; ++h) {
        kkA[h] = *(const float4*)(kkbase + h * FF);
        kkB[h] = *(const float4*)(kkbase + h * FF + 4);
        qv[h]  = *(const float2*)(qbase + h * DD);
    }

    float m[HH] = {-INFINITY, -INFINITY, -INFINITY, -INFINITY};
    bool fast = (cnt <= 128);

    for (int c0 = 0; c0 < cnt; c0 += 64) {
        int nc = min(cnt - c0, 64);
        int pv = 0, dv = 0;
        if (lane < nc) { pv = perm[base + c0 + lane]; dv = dsts[base + c0 + lane]; }
        for (int j0 = 0; j0 < nc; j0 += 4) {
            float ev[HH]; int e_i;
            int idx = score4(rel, k, pv, dv, j0, g, t, kkA, kkB, qv, ev, &e_i);
            if (idx < nc) {
#pragma unroll
                for (int h = 0; h < HH; ++h) m[h] = fmaxf(m[h], ev[h]);
                if (fast && t == 0)
                    *(float4*)e_buf[c0 + idx] = make_float4(ev[0], ev[1], ev[2], ev[3]);
            }
        }
    }
#pragma unroll
    for (int h = 0; h < HH; ++h) {
        m[h] = fmaxf(m[h], __shfl_xor(m[h], 16, 64));
        m[h] = fmaxf(m[h], __shfl_xor(m[h], 32, 64));
    }

    if (fast) {
        int i0 = lane, i1 = lane + 64;
        float ex0[HH] = {0.f, 0.f, 0.f, 0.f}, ex1[HH] = {0.f, 0.f, 0.f, 0.f};
        if (i0 < cnt) {
            float4 ev = *(const float4*)e_buf[i0];
            ex0[0] = __expf(ev.x - m[0]); ex0[1] = __expf(ev.y - m[1]);
            ex0[2] = __expf(ev.z - m[2]); ex0[3] = __expf(ev.w - m[3]);
        }
        if (i1 < cnt) {
            float4 ev = *(const float4*)e_buf[i1];
            ex1[0] = __expf(ev.x - m[0]); ex1[1] = __expf(ev.y - m[1]);
            ex1[2] = __expf(ev.z - m[2]); ex1[3] = __expf(ev.w - m[3]);
        }
        float rl[HH];
#pragma unroll
        for (int h = 0; h < HH; ++h) {
            float v = ex0[h] + ex1[h];
#pragma unroll
            for (int off = 1; off < 64; off <<= 1) v += __shfl_xor(v, off, 64);
            rl[h] = 1.0f / v;
        }
        if (i0 < cnt)
            out[perm[base + i0]] = 0.25f * (ex0[0]*rl[0] + ex0[1]*rl[1] + ex0[2]*rl[2] + ex0[3]*rl[3]);
        if (i1 < cnt)
            out[perm[base + i1]] = 0.25f * (ex1[0]*rl[0] + ex1[1]*rl[1] + ex1[2]*rl[2] + ex1[3]*rl[3]);
    } else {
        // slow path (cnt > 128): recompute scores; correctness-only, ~never taken
        float lacc[HH] = {0.f, 0.f, 0.f, 0.f};
        for (int c0 = 0; c0 < cnt; c0 += 64) {
            int nc = min(cnt - c0, 64);
            int pv = 0, dv = 0;
            if (lane < nc) { pv = perm[base + c0 + lane]; dv = dsts[base + c0 + lane]; }
            for (int j0 = 0; j0 < nc; j0 += 4) {
                float ev[HH]; int e_i;
                int idx = score4(rel, k, pv, dv, j0, g, t, kkA, kkB, qv, ev, &e_i);
                if (idx < nc && t == 0) {
#pragma unroll
                    for (int h = 0; h < HH; ++h) lacc[h] += __expf(ev[h] - m[h]);
                }
            }
        }
        float rl[HH];
#pragma unroll
        for (int h = 0; h < HH; ++h) {
            float v = lacc[h];
#pragma unroll
            for (int off = 1; off < 64; off <<= 1) v += __shfl_xor(v, off, 64);
            rl[h] = 1.0f / v;
        }
        for (int c0 = 0; c0 < cnt; c0 += 64) {
            int nc = min(cnt - c0, 64);
            int pv = 0, dv = 0;
            if (lane < nc) { pv = perm[base + c0 + lane]; dv = dsts[base + c0 + lane]; }
            for (int j0 = 0; j0 < nc; j0 += 4) {
                float ev[HH]; int e_i;
                int idx = score4(rel, k, pv, dv, j0, g, t, kkA, kkB, qv, ev, &e_i);
                if (idx < nc && t == 0) {
                    float a = __expf(ev[0]-m[0])*rl[0] + __expf(ev[1]-m[1])*rl[1]
                            + __expf(ev[2]-m[2])*rl[2] + __expf(ev[3]-m[3])*rl[3];
                    out[e_i] = 0.25f * a;
                }
            }
        }
    }
}

extern "C" void kernel_launch(void* const* d_in, const int* in_sizes, int n_in,
                              void* d_out, int out_size, void* d_ws, size_t ws_size,
                              hipStream_t stream) {
    const float* feat = (const float*)d_in[0];   // (N,1,F)
    const float* rel  = (const float*)d_in[1];   // (E,1,F)
    const int*   src  = (const int*)d_in[2];
    const int*   dst  = (const int*)d_in[3];
    const float* wq   = (const float*)d_in[4];   // (H,F,D)
    const float* wk   = (const float*)d_in[5];
    float* out = (float*)d_out;

    const int N = in_sizes[0] / FF;
    const int E = in_sizes[2];

    float* q      = (float*)d_ws;                     // N*H*D
    float* k      = q  + (size_t)N * HH * DD;         // N*H*D
    float* kk     = k  + (size_t)N * HH * DD;         // N*H*F
    int*   counts = (int*)(kk + (size_t)N * HH * FF); // N
    int*   start  = counts + N;                       // N
    int*   cursor = start + N;                        // N
    int*   partial= cursor + N;                       // 256
    int*   perm   = partial + 256;                    // E
    int*   dsts   = perm + E;                         // E

    int nb  = (N + 255) / 256;      // 196 <= 256: single-block partial scan ok
    int QKB = (N + 31) / 32;
    int HB  = (E + 1023) / 1024;
    int KKB = (N + 15) / 16;

    zero_kernel<<<nb, 256, 0, stream>>>(counts, N);
    qk_hist_kernel<<<QKB + HB, 256, 0, stream>>>(feat, wq, wk, q, k, N, src, counts, E, QKB);
    kk_scan_kernel<<<KKB + nb, 256, 0, stream>>>(k, wk, kk, N, counts, start, partial, KKB);
    scan_partial_kernel<<<1, 256, 0, stream>>>(partial, nb);
    addback_kernel<<<nb, 256, 0, stream>>>(start, cursor, partial, N);
    scatter_kernel<<<(E + 255) / 256, 256, 0, stream>>>(src, dst, cursor, perm, dsts, E);
    group_kernel<<<(N + 3) / 4, 256, 0, stream>>>(rel, perm, dsts, q, k, kk, start, counts, out, N);
}